// Round 19
// baseline (64.021 us; speedup 1.0000x reference)
//
#include <hip/hip_runtime.h>
#include <hip/hip_bf16.h>

#define B_ 8
#define S_ 2048
#define D_ 1024
#define H_ 64

typedef __attribute__((ext_vector_type(8))) short bf16x8;
typedef __attribute__((ext_vector_type(4))) float f32x4;
typedef __attribute__((ext_vector_type(4))) unsigned short u16x4;
typedef unsigned short u16;
typedef unsigned int u32;

// fold 1/sqrt(64) and log2(e) into Q so softmax can use exp2
#define QSCALE 0.18033688011112042f

static __device__ __forceinline__ u16 f2bf(float f) {
  union { float f; unsigned u; } v; v.f = f;
  unsigned r = v.u + 0x7FFFu + ((v.u >> 16) & 1u);
  return (u16)(r >> 16);
}

// wprep v2: coalesced LDS-transpose build of Wt [192][1024] bf16.
// Grid = 3 W-matrices x 16 d-chunks = 48 blocks x 256 threads.
// Reads W[d][h] coalesced (row-major), writes Wt[c][d] coalesced.
__global__ __launch_bounds__(256) void wprep_kernel(const float* __restrict__ Wk,
                                                    const float* __restrict__ Wq,
                                                    const float* __restrict__ Wv,
                                                    u16* __restrict__ Wt) {
  __shared__ float lds[64][65];
  const int wsel = blockIdx.x >> 4;        // 0=Q,1=K,2=V
  const int d0 = (blockIdx.x & 15) << 6;   // d-chunk base
  const float* W = (wsel == 0) ? Wq : ((wsel == 1) ? Wk : Wv);
  const int cbase = wsel << 6;
  const int tid = threadIdx.x;

#pragma unroll
  for (int e = 0; e < 16; ++e) {
    const int idx = e * 256 + tid;
    const int dd = idx >> 6, h = idx & 63;
    lds[dd][h] = W[(size_t)(d0 + dd) * H_ + h];
  }
  __syncthreads();
#pragma unroll
  for (int e = 0; e < 16; ++e) {
    const int idx = e * 256 + tid;
    const int c = idx >> 6, dd = idx & 63;
    Wt[(size_t)(cbase + c) * D_ + d0 + dd] = f2bf(lds[dd][c]);
  }
}

// QKV v15: v13's LDS-DMA dbuf pipeline with 64-row blocks.
// Grid = 256 blocks x 1024 threads = 16 waves = 4 row-groups x 4 col-groups
// over 64 rows x 192 cols; BK=64, 16 chunks; LDS 80 KB -> 1 block/CU =
// 16 waves/CU (same TLP as v13, half the W re-stage traffic).
// Batch->XCD pinning: bpin = blockIdx&7.
__global__ __launch_bounds__(1024, 4) void qkv_kernel(const float* __restrict__ x,
                                                      const u16* __restrict__ Wt,
                                                      u16* __restrict__ Qb,
                                                      u16* __restrict__ Kb,
                                                      u16* __restrict__ Vt) {
  __shared__ char sh[81920];  // xs: 2 x [64][64] f32 (32 KB); ws: 2 x [192][64] bf16 (48 KB)
  char* const xsb = sh;
  char* const wsb = sh + 32768;

  const int tid = threadIdx.x;
  const int w = tid >> 6;      // 0..15
  const int lane = tid & 63;
  const int r = lane & 15;
  const int g = lane >> 4;
  const int rg = w >> 2;       // row-group 0..3
  const int cg = w & 3;        // col-group 0..3

  const int bpin = blockIdx.x & 7;       // batch == XCD
  const int jj = blockIdx.x >> 3;        // 0..31 row-group within batch
  const long row0 = ((long)bpin * 32 + jj) * 64;

  // x tile [64 rows][64 k] f32, row stride 256 B; swizzle bits 4-6 by row&7.
  // 16 KB = 1 load/thread.
#define STAGE_X(kc, buf)                                                       \
  {                                                                            \
    const char* gb = (const char*)x + (size_t)row0 * 4096 + (size_t)(kc) * 256;\
    const int L = tid * 16;                                                    \
    const int row = L >> 8;                                                    \
    const int sw = (L & 255) ^ ((row & 7) << 4);                               \
    __builtin_amdgcn_global_load_lds(                                          \
        (const __attribute__((address_space(1))) u32*)(gb + (size_t)row * 4096 + sw), \
        (__attribute__((address_space(3))) u32*)(xsb + (buf) * 16384 + L),     \
        16, 0, 0);                                                             \
  }

  // W tile [192 cols][64 k] bf16, col stride 128 B; swizzle bits 4-6 by col&7.
  // 24 KB: j2=0 all threads, j2=1 tid<512.
#define STAGE_W(kc, buf)                                                       \
  {                                                                            \
    const char* gb = (const char*)Wt + (size_t)(kc) * 128;                     \
    _Pragma("unroll") for (int j2 = 0; j2 < 2; ++j2) {                         \
      const int L = j2 * 16384 + tid * 16;                                     \
      if (L < 24576) {                                                         \
        const int col = L >> 7;                                                \
        const int sw = (L & 127) ^ ((col & 7) << 4);                           \
        __builtin_amdgcn_global_load_lds(                                      \
            (const __attribute__((address_space(1))) u32*)(gb + (size_t)col * 2048 + sw), \
            (__attribute__((address_space(3))) u32*)(wsb + (buf) * 24576 + L), \
            16, 0, 0);                                                         \
      }                                                                        \
    }                                                                          \
  }

  f32x4 acc[3];
#pragma unroll
  for (int nf = 0; nf < 3; ++nf) acc[nf] = (f32x4){0.f, 0.f, 0.f, 0.f};

  STAGE_X(0, 0);
  STAGE_W(0, 0);
  int cur = 0;

  const int rr = rg * 16 + r;            // 0..63
  const int xswz = (rr & 7) << 4;

  for (int kc = 0; kc < 16; ++kc) {
    __syncthreads();  // stage(kc) complete (vmcnt drained here, by design)
    if (kc < 15) {
      STAGE_X(kc + 1, cur ^ 1);
      STAGE_W(kc + 1, cur ^ 1);
    }
    __builtin_amdgcn_sched_barrier(0);  // keep stage issue above compute

    const char* xb = xsb + cur * 16384;
    const char* wb = wsb + cur * 24576;
#pragma unroll
    for (int ks = 0; ks < 2; ++ks) {
      const int cb = ks * 128 + g * 32;
      const float4 lo = *(const float4*)(xb + rr * 256 + (cb ^ xswz));
      const float4 hi = *(const float4*)(xb + rr * 256 + ((cb + 16) ^ xswz));
      bf16x8 a;
      a[0] = (short)f2bf(lo.x); a[1] = (short)f2bf(lo.y);
      a[2] = (short)f2bf(lo.z); a[3] = (short)f2bf(lo.w);
      a[4] = (short)f2bf(hi.x); a[5] = (short)f2bf(hi.y);
      a[6] = (short)f2bf(hi.z); a[7] = (short)f2bf(hi.w);
#pragma unroll
      for (int nf = 0; nf < 3; ++nf) {
        const int col = cg * 48 + nf * 16 + r;
        const int wcb = (ks * 64 + g * 16) ^ ((col & 7) << 4);
        const bf16x8 b = *(const bf16x8*)(wb + col * 128 + wcb);
        acc[nf] = __builtin_amdgcn_mfma_f32_16x16x32_bf16(a, b, acc[nf], 0, 0, 0);
      }
    }
    cur ^= 1;
  }
#undef STAGE_W
#undef STAGE_X

  // ---- epilogue: wave owns rows rg*16..+15, cols cg*48..+47 exclusively ----
  const int bb = (int)(row0 >> 11);
  const int srow = (int)(row0 & 2047) + rg * 16;
#pragma unroll
  for (int nf = 0; nf < 3; ++nf) {
    const int col = cg * 48 + nf * 16 + r;  // frag wholly in Q, K, or V
    if (col < 64) {
#pragma unroll
      for (int ii = 0; ii < 4; ++ii)
        Qb[(row0 + rg * 16 + 4 * g + ii) * H_ + col] = f2bf(acc[nf][ii] * QSCALE);
    } else if (col < 128) {
#pragma unroll
      for (int ii = 0; ii < 4; ++ii)
        Kb[(row0 + rg * 16 + 4 * g + ii) * H_ + (col - 64)] = f2bf(acc[nf][ii]);
    } else {
      u16x4 vp;
#pragma unroll
      for (int ii = 0; ii < 4; ++ii) vp[ii] = f2bf(acc[nf][ii]);
      *(u16x4*)(Vt + ((size_t)(bb * H_ + (col - 128))) * S_ + srow + 4 * g) = vp;
    }
  }
}

// attn7 + XCD pinning + s_setprio (round-18 verbatim, ~24-25 us inferred).
__global__ __launch_bounds__(256, 2) void attn7_kernel(const u16* __restrict__ Qb,
                                                       const u16* __restrict__ Kb,
                                                       const u16* __restrict__ Vt,
                                                       float* __restrict__ out) {
  __shared__ u16 plds[4][16 * 72];
  __shared__ float plo[4][16][68];
  __shared__ float pml[4][2][16];

  const int b = blockIdx.x & 7;        // batch == XCD
  const int j = blockIdx.x >> 3;       // 0..63
  const int w = threadIdx.x >> 6;
  const int lane = threadIdx.x & 63;
  const int r = lane & 15;
  const int g = lane >> 4;

  const int qt = (w < 2) ? j : (127 - j);
  const int s = w & 1;
  const int q0 = qt << 4;
  const int T = (qt >> 2) + 1;          // # of 64-wide kv tiles
  const int half = (T + 1) >> 1;
  const int start = s ? half : 0;
  const int end = s ? T : half;

  // Q as B-operand: b[i] = Q[q=r][8g+i]
  const u16* Qp = Qb + ((long)(b * S_ + q0 + r)) * H_ + 8 * g;
  const bf16x8 bq0 = *(const bf16x8*)Qp;
  const bf16x8 bq1 = *(const bf16x8*)(Qp + 32);

  const u16* Kbase = Kb + (long)b * S_ * H_ + (long)r * H_ + 8 * g;
  const u16* Vbase = Vt + (long)b * H_ * S_ + (long)r * S_ + 8 * g;

  f32x4 o[4];
#pragma unroll
  for (int nf = 0; nf < 4; ++nf) o[nf] = (f32x4){0.f, 0.f, 0.f, 0.f};
  float m = -INFINITY, l = 0.f;

  u16* pw = plds[w];

  bf16x8 ka[8];  // K as A-operand: a[i] = K[k0+16kf+r][8g+i]
  if (start < end) {
    const int k0 = start << 6;
#pragma unroll
    for (int kf = 0; kf < 4; ++kf) {
      const u16* Kp = Kbase + (long)(k0 + kf * 16) * H_;
      ka[2 * kf] = *(const bf16x8*)(Kp);
      ka[2 * kf + 1] = *(const bf16x8*)(Kp + 32);
    }
  }

  for (int kt = start; kt < end; ++kt) {
    const int k0 = kt << 6;

    // ---- S^T tile [64k x 16q]: rows k (4g+i within 16kf), col q=r ----
    f32x4 t4[4];
    __builtin_amdgcn_s_setprio(1);
#pragma unroll
    for (int kf = 0; kf < 4; ++kf) {
      f32x4 t = (f32x4){0.f, 0.f, 0.f, 0.f};
      t = __builtin_amdgcn_mfma_f32_16x16x32_bf16(ka[2 * kf], bq0, t, 0, 0, 0);
      t = __builtin_amdgcn_mfma_f32_16x16x32_bf16(ka[2 * kf + 1], bq1, t, 0, 0, 0);
      t4[kf] = t;
    }
    __builtin_amdgcn_s_setprio(0);

    // ---- early V loads (fly under softmax) ----
    bf16x8 vv[8];
#pragma unroll
    for (int nf = 0; nf < 4; ++nf) {
      const u16* Vp = Vbase + (long)(nf * 16) * S_ + k0;
      vv[2 * nf] = *(const bf16x8*)(Vp);
      vv[2 * nf + 1] = *(const bf16x8*)(Vp + 32);
    }
    // ---- prefetch next K tile ----
    if (kt + 1 < end) {
      const int kn = (kt + 1) << 6;
#pragma unroll
      for (int kf = 0; kf < 4; ++kf) {
        const u16* Kp = Kbase + (long)(kn + kf * 16) * H_;
        ka[2 * kf] = *(const bf16x8*)(Kp);
        ka[2 * kf + 1] = *(const bf16x8*)(Kp + 32);
      }
    }

    if (kt == T - 1) {  // diagonal tile: causal mask (k > q)
#pragma unroll
      for (int kf = 0; kf < 4; ++kf)
#pragma unroll
        for (int i = 0; i < 4; ++i) {
          const int k = k0 + kf * 16 + 4 * g + i;
          if (k > q0 + r) t4[kf][i] = -INFINITY;
        }
    }

    // ---- row max: 15 in-lane + 2 shfl (row q=r replicated over g) ----
    float pm = t4[0][0];
#pragma unroll
    for (int kf = 0; kf < 4; ++kf)
#pragma unroll
      for (int i = 0; i < 4; ++i) pm = fmaxf(pm, t4[kf][i]);
    pm = fmaxf(pm, __shfl_xor(pm, 16));
    pm = fmaxf(pm, __shfl_xor(pm, 32));

    // ---- defer-max: rescale only when max grew past threshold ----
    if (__any(pm > m + 8.f)) {
      const float mn = fmaxf(m, pm);
      const float sc = exp2f(m - mn);
      m = mn;
      l *= sc;
      float scr[4];
#pragma unroll
      for (int i = 0; i < 4; ++i) scr[i] = __shfl(sc, 4 * g + i);  // o rows = 4g+i
#pragma unroll
      for (int nf = 0; nf < 4; ++nf)
#pragma unroll
        for (int i = 0; i < 4; ++i) o[nf][i] *= scr[i];
    }

    // ---- P = exp2(S - m), in-lane sum + 2 shfl ----
    float ps = 0.f;
#pragma unroll
    for (int kf = 0; kf < 4; ++kf)
#pragma unroll
      for (int i = 0; i < 4; ++i) {
        const float p = exp2f(t4[kf][i] - m);
        t4[kf][i] = p;
        ps += p;
      }
    ps += __shfl_xor(ps, 16);
    ps += __shfl_xor(ps, 32);
    l += ps;

    // ---- P -> LDS: 4x ds_write_b64 (row q=r, k contiguous) ----
#pragma unroll
    for (int kf = 0; kf < 4; ++kf) {
      u16x4 pk;
#pragma unroll
      for (int i = 0; i < 4; ++i) pk[i] = f2bf(t4[kf][i]);
      *(u16x4*)(pw + r * 72 + kf * 16 + 4 * g) = pk;
    }

    const bf16x8 pa0 = *(const bf16x8*)(pw + r * 72 + 8 * g);
    const bf16x8 pa1 = *(const bf16x8*)(pw + r * 72 + 32 + 8 * g);

    // ---- PV: O[16q x 64h] += P * V ----
    __builtin_amdgcn_s_setprio(1);
#pragma unroll
    for (int nf = 0; nf < 4; ++nf) {
      o[nf] = __builtin_amdgcn_mfma_f32_16x16x32_bf16(pa0, vv[2 * nf], o[nf], 0, 0, 0);
      o[nf] = __builtin_amdgcn_mfma_f32_16x16x32_bf16(pa1, vv[2 * nf + 1], o[nf], 0, 0, 0);
    }
    __builtin_amdgcn_s_setprio(0);
  }

  // ---- write partials (o rows = 4g+i; m,l live at lane r = row) ----
#pragma unroll
  for (int nf = 0; nf < 4; ++nf)
#pragma unroll
    for (int i = 0; i < 4; ++i)
      plo[w][4 * g + i][nf * 16 + r] = o[nf][i];
  if (g == 0) {
    pml[w][0][r] = m;
    pml[w][1][r] = l;
  }
  __syncthreads();

  // ---- merge the two kv-halves; each wave writes 8 rows of one q-tile ----
  const int base = (w >> 1) << 1;
  const int hlf = w & 1;
  const int qq0 = ((base == 0) ? j : (127 - j)) << 4;
#pragma unroll
  for (int rr = 0; rr < 8; ++rr) {
    const int row = hlf * 8 + rr;
    const float mA = pml[base][0][row], mB = pml[base + 1][0][row];
    const float lA = pml[base][1][row], lB = pml[base + 1][1][row];
    const float M = fmaxf(mA, mB);
    const float ea = exp2f(mA - M), eb = exp2f(mB - M);
    const float inv = 1.f / (lA * ea + lB * eb);
    const float oo = plo[base][row][lane] * ea + plo[base + 1][row][lane] * eb;
    out[((long)(b * S_ + qq0 + row)) * H_ + lane] = oo * inv;
  }
}

extern "C" void kernel_launch(void* const* d_in, const int* in_sizes, int n_in,
                              void* d_out, int out_size, void* d_ws, size_t ws_size,
                              hipStream_t stream) {
  const float* x  = (const float*)d_in[0];
  const float* Wk = (const float*)d_in[1];
  const float* Wq = (const float*)d_in[2];
  const float* Wv = (const float*)d_in[3];
  float* out = (float*)d_out;

  u16* Qb = (u16*)d_ws;                                   // 2 MiB
  u16* Kb = Qb + (long)B_ * S_ * H_;                      // 2 MiB
  u16* Vt = Kb + (long)B_ * S_ * H_;                      // 2 MiB
  u16* Wt = Vt + (long)B_ * S_ * H_;                      // 384 KiB

  wprep_kernel<<<48, 256, 0, stream>>>(Wk, Wq, Wv, Wt);
  qkv_kernel<<<256, 1024, 0, stream>>>(x, Wt, Qb, Kb, Vt);
  attn7_kernel<<<B_ * 64, 256, 0, stream>>>(Qb, Kb, Vt, out);
}

// Round 20
// 60.423 us; speedup vs baseline: 1.0595x; 1.0595x over previous
//
#include <hip/hip_runtime.h>
#include <hip/hip_bf16.h>

#define B_ 8
#define S_ 2048
#define D_ 1024
#define H_ 64

typedef __attribute__((ext_vector_type(8))) short bf16x8;
typedef __attribute__((ext_vector_type(4))) float f32x4;
typedef __attribute__((ext_vector_type(4))) unsigned short u16x4;
typedef unsigned short u16;
typedef unsigned int u32;

// fold 1/sqrt(64) and log2(e) into Q so softmax can use exp2
#define QSCALE 0.18033688011112042f

static __device__ __forceinline__ u16 f2bf(float f) {
  union { float f; unsigned u; } v; v.f = f;
  unsigned r = v.u + 0x7FFFu + ((v.u >> 16) & 1u);
  return (u16)(r >> 16);
}

// wprep v2: coalesced LDS-transpose build of Wt [192][1024] bf16.
// Grid = 3 W-matrices x 16 d-chunks = 48 blocks x 256 threads.
__global__ __launch_bounds__(256) void wprep_kernel(const float* __restrict__ Wk,
                                                    const float* __restrict__ Wq,
                                                    const float* __restrict__ Wv,
                                                    u16* __restrict__ Wt) {
  __shared__ float lds[64][65];
  const int wsel = blockIdx.x >> 4;        // 0=Q,1=K,2=V
  const int d0 = (blockIdx.x & 15) << 6;   // d-chunk base
  const float* W = (wsel == 0) ? Wq : ((wsel == 1) ? Wk : Wv);
  const int cbase = wsel << 6;
  const int tid = threadIdx.x;

#pragma unroll
  for (int e = 0; e < 16; ++e) {
    const int idx = e * 256 + tid;
    const int dd = idx >> 6, h = idx & 63;
    lds[dd][h] = W[(size_t)(d0 + dd) * H_ + h];
  }
  __syncthreads();
#pragma unroll
  for (int e = 0; e < 16; ++e) {
    const int idx = e * 256 + tid;
    const int c = idx >> 6, dd = idx & 63;
    Wt[(size_t)(cbase + c) * D_ + d0 + dd] = f2bf(lds[dd][c]);
  }
}

// QKV v13 (round-16/18 verbatim): 8-wave LDS-DMA dbuf pipeline + batch->XCD
// pinning. Block = 4 col-groups x 2 row-groups over 32 rows x 192 cols;
// BK=64, 16 chunks; 64 KB LDS -> 2 blocks/CU = 16 waves/CU.
__global__ __launch_bounds__(512, 4) void qkv_kernel(const float* __restrict__ x,
                                                     const u16* __restrict__ Wt,
                                                     u16* __restrict__ Qb,
                                                     u16* __restrict__ Kb,
                                                     u16* __restrict__ Vt) {
  __shared__ char sh[65536];  // xs: 2 x [32][64] f32 (16 KB); ws: 2 x [192][64] bf16 (48 KB)
  char* const xsb = sh;
  char* const wsb = sh + 16384;

  const int tid = threadIdx.x;
  const int w = tid >> 6;
  const int lane = tid & 63;
  const int r = lane & 15;
  const int g = lane >> 4;
  const int rg = w >> 2;   // row-group 0/1
  const int cg = w & 3;    // col-group 0..3

  const int bpin = blockIdx.x & 7;       // batch == XCD
  const int jj = blockIdx.x >> 3;        // 0..63 row-group within batch
  const long row0 = ((long)bpin * 64 + jj) * 32;

#define STAGE_X(kc, buf)                                                       \
  {                                                                            \
    const char* gb = (const char*)x + (size_t)row0 * 4096 + (size_t)(kc) * 256;\
    const int L = tid * 16;                                                    \
    const int row = L >> 8;                                                    \
    const int sw = (L & 255) ^ ((row & 7) << 4);                               \
    __builtin_amdgcn_global_load_lds(                                          \
        (const __attribute__((address_space(1))) u32*)(gb + (size_t)row * 4096 + sw), \
        (__attribute__((address_space(3))) u32*)(xsb + (buf) * 8192 + L),      \
        16, 0, 0);                                                             \
  }

#define STAGE_W(kc, buf)                                                       \
  {                                                                            \
    const char* gb = (const char*)Wt + (size_t)(kc) * 128;                     \
    _Pragma("unroll") for (int j2 = 0; j2 < 3; ++j2) {                         \
      const int L = j2 * 8192 + tid * 16;                                      \
      const int col = L >> 7;                                                  \
      const int sw = (L & 127) ^ ((col & 7) << 4);                             \
      __builtin_amdgcn_global_load_lds(                                        \
          (const __attribute__((address_space(1))) u32*)(gb + (size_t)col * 2048 + sw), \
          (__attribute__((address_space(3))) u32*)(wsb + (buf) * 24576 + L),   \
          16, 0, 0);                                                           \
    }                                                                          \
  }

  f32x4 acc[3];
#pragma unroll
  for (int nf = 0; nf < 3; ++nf) acc[nf] = (f32x4){0.f, 0.f, 0.f, 0.f};

  STAGE_X(0, 0);
  STAGE_W(0, 0);
  int cur = 0;

  const int rr = rg * 16 + r;
  const int xswz = (rr & 7) << 4;

  for (int kc = 0; kc < 16; ++kc) {
    __syncthreads();  // stage(kc) complete (vmcnt drained here, by design)
    if (kc < 15) {
      STAGE_X(kc + 1, cur ^ 1);
      STAGE_W(kc + 1, cur ^ 1);
    }
    __builtin_amdgcn_sched_barrier(0);  // keep stage issue above compute

    const char* xb = xsb + cur * 8192;
    const char* wb = wsb + cur * 24576;
#pragma unroll
    for (int ks = 0; ks < 2; ++ks) {
      const int cb = ks * 128 + g * 32;
      const float4 lo = *(const float4*)(xb + rr * 256 + (cb ^ xswz));
      const float4 hi = *(const float4*)(xb + rr * 256 + ((cb + 16) ^ xswz));
      bf16x8 a;
      a[0] = (short)f2bf(lo.x); a[1] = (short)f2bf(lo.y);
      a[2] = (short)f2bf(lo.z); a[3] = (short)f2bf(lo.w);
      a[4] = (short)f2bf(hi.x); a[5] = (short)f2bf(hi.y);
      a[6] = (short)f2bf(hi.z); a[7] = (short)f2bf(hi.w);
#pragma unroll
      for (int nf = 0; nf < 3; ++nf) {
        const int col = cg * 48 + nf * 16 + r;
        const int wcb = (ks * 64 + g * 16) ^ ((col & 7) << 4);
        const bf16x8 b = *(const bf16x8*)(wb + col * 128 + wcb);
        acc[nf] = __builtin_amdgcn_mfma_f32_16x16x32_bf16(a, b, acc[nf], 0, 0, 0);
      }
    }
    cur ^= 1;
  }
#undef STAGE_W
#undef STAGE_X

  // ---- epilogue: wave owns rows rg*16..+15, cols cg*48..+47 exclusively ----
  const int bb = (int)(row0 >> 11);
  const int srow = (int)(row0 & 2047) + rg * 16;
#pragma unroll
  for (int nf = 0; nf < 3; ++nf) {
    const int col = cg * 48 + nf * 16 + r;  // frag wholly in Q, K, or V
    if (col < 64) {
#pragma unroll
      for (int ii = 0; ii < 4; ++ii)
        Qb[(row0 + rg * 16 + 4 * g + ii) * H_ + col] = f2bf(acc[nf][ii] * QSCALE);
    } else if (col < 128) {
#pragma unroll
      for (int ii = 0; ii < 4; ++ii)
        Kb[(row0 + rg * 16 + 4 * g + ii) * H_ + (col - 64)] = f2bf(acc[nf][ii]);
    } else {
      u16x4 vp;
#pragma unroll
      for (int ii = 0; ii < 4; ++ii) vp[ii] = f2bf(acc[nf][ii]);
      *(u16x4*)(Vt + ((size_t)(bb * H_ + (col - 128))) * S_ + srow + 4 * g) = vp;
    }
  }
}

// attn7 + XCD pinning + s_setprio (round-18 verbatim).
__global__ __launch_bounds__(256, 2) void attn7_kernel(const u16* __restrict__ Qb,
                                                       const u16* __restrict__ Kb,
                                                       const u16* __restrict__ Vt,
                                                       float* __restrict__ out) {
  __shared__ u16 plds[4][16 * 72];
  __shared__ float plo[4][16][68];
  __shared__ float pml[4][2][16];

  const int b = blockIdx.x & 7;        // batch == XCD
  const int j = blockIdx.x >> 3;       // 0..63
  const int w = threadIdx.x >> 6;
  const int lane = threadIdx.x & 63;
  const int r = lane & 15;
  const int g = lane >> 4;

  const int qt = (w < 2) ? j : (127 - j);
  const int s = w & 1;
  const int q0 = qt << 4;
  const int T = (qt >> 2) + 1;          // # of 64-wide kv tiles
  const int half = (T + 1) >> 1;
  const int start = s ? half : 0;
  const int end = s ? T : half;

  // Q as B-operand: b[i] = Q[q=r][8g+i]
  const u16* Qp = Qb + ((long)(b * S_ + q0 + r)) * H_ + 8 * g;
  const bf16x8 bq0 = *(const bf16x8*)Qp;
  const bf16x8 bq1 = *(const bf16x8*)(Qp + 32);

  const u16* Kbase = Kb + (long)b * S_ * H_ + (long)r * H_ + 8 * g;
  const u16* Vbase = Vt + (long)b * H_ * S_ + (long)r * S_ + 8 * g;

  f32x4 o[4];
#pragma unroll
  for (int nf = 0; nf < 4; ++nf) o[nf] = (f32x4){0.f, 0.f, 0.f, 0.f};
  float m = -INFINITY, l = 0.f;

  u16* pw = plds[w];

  bf16x8 ka[8];  // K as A-operand: a[i] = K[k0+16kf+r][8g+i]
  if (start < end) {
    const int k0 = start << 6;
#pragma unroll
    for (int kf = 0; kf < 4; ++kf) {
      const u16* Kp = Kbase + (long)(k0 + kf * 16) * H_;
      ka[2 * kf] = *(const bf16x8*)(Kp);
      ka[2 * kf + 1] = *(const bf16x8*)(Kp + 32);
    }
  }

  for (int kt = start; kt < end; ++kt) {
    const int k0 = kt << 6;

    // ---- S^T tile [64k x 16q]: rows k (4g+i within 16kf), col q=r ----
    f32x4 t4[4];
    __builtin_amdgcn_s_setprio(1);
#pragma unroll
    for (int kf = 0; kf < 4; ++kf) {
      f32x4 t = (f32x4){0.f, 0.f, 0.f, 0.f};
      t = __builtin_amdgcn_mfma_f32_16x16x32_bf16(ka[2 * kf], bq0, t, 0, 0, 0);
      t = __builtin_amdgcn_mfma_f32_16x16x32_bf16(ka[2 * kf + 1], bq1, t, 0, 0, 0);
      t4[kf] = t;
    }
    __builtin_amdgcn_s_setprio(0);

    // ---- early V loads (fly under softmax) ----
    bf16x8 vv[8];
#pragma unroll
    for (int nf = 0; nf < 4; ++nf) {
      const u16* Vp = Vbase + (long)(nf * 16) * S_ + k0;
      vv[2 * nf] = *(const bf16x8*)(Vp);
      vv[2 * nf + 1] = *(const bf16x8*)(Vp + 32);
    }
    // ---- prefetch next K tile ----
    if (kt + 1 < end) {
      const int kn = (kt + 1) << 6;
#pragma unroll
      for (int kf = 0; kf < 4; ++kf) {
        const u16* Kp = Kbase + (long)(kn + kf * 16) * H_;
        ka[2 * kf] = *(const bf16x8*)(Kp);
        ka[2 * kf + 1] = *(const bf16x8*)(Kp + 32);
      }
    }

    if (kt == T - 1) {  // diagonal tile: causal mask (k > q)
#pragma unroll
      for (int kf = 0; kf < 4; ++kf)
#pragma unroll
        for (int i = 0; i < 4; ++i) {
          const int k = k0 + kf * 16 + 4 * g + i;
          if (k > q0 + r) t4[kf][i] = -INFINITY;
        }
    }

    // ---- row max: 15 in-lane + 2 shfl (row q=r replicated over g) ----
    float pm = t4[0][0];
#pragma unroll
    for (int kf = 0; kf < 4; ++kf)
#pragma unroll
      for (int i = 0; i < 4; ++i) pm = fmaxf(pm, t4[kf][i]);
    pm = fmaxf(pm, __shfl_xor(pm, 16));
    pm = fmaxf(pm, __shfl_xor(pm, 32));

    // ---- defer-max: rescale only when max grew past threshold ----
    if (__any(pm > m + 8.f)) {
      const float mn = fmaxf(m, pm);
      const float sc = exp2f(m - mn);
      m = mn;
      l *= sc;
      float scr[4];
#pragma unroll
      for (int i = 0; i < 4; ++i) scr[i] = __shfl(sc, 4 * g + i);  // o rows = 4g+i
#pragma unroll
      for (int nf = 0; nf < 4; ++nf)
#pragma unroll
        for (int i = 0; i < 4; ++i) o[nf][i] *= scr[i];
    }

    // ---- P = exp2(S - m), in-lane sum + 2 shfl ----
    float ps = 0.f;
#pragma unroll
    for (int kf = 0; kf < 4; ++kf)
#pragma unroll
      for (int i = 0; i < 4; ++i) {
        const float p = exp2f(t4[kf][i] - m);
        t4[kf][i] = p;
        ps += p;
      }
    ps += __shfl_xor(ps, 16);
    ps += __shfl_xor(ps, 32);
    l += ps;

    // ---- P -> LDS: 4x ds_write_b64 (row q=r, k contiguous) ----
#pragma unroll
    for (int kf = 0; kf < 4; ++kf) {
      u16x4 pk;
#pragma unroll
      for (int i = 0; i < 4; ++i) pk[i] = f2bf(t4[kf][i]);
      *(u16x4*)(pw + r * 72 + kf * 16 + 4 * g) = pk;
    }

    const bf16x8 pa0 = *(const bf16x8*)(pw + r * 72 + 8 * g);
    const bf16x8 pa1 = *(const bf16x8*)(pw + r * 72 + 32 + 8 * g);

    // ---- PV: O[16q x 64h] += P * V ----
    __builtin_amdgcn_s_setprio(1);
#pragma unroll
    for (int nf = 0; nf < 4; ++nf) {
      o[nf] = __builtin_amdgcn_mfma_f32_16x16x32_bf16(pa0, vv[2 * nf], o[nf], 0, 0, 0);
      o[nf] = __builtin_amdgcn_mfma_f32_16x16x32_bf16(pa1, vv[2 * nf + 1], o[nf], 0, 0, 0);
    }
    __builtin_amdgcn_s_setprio(0);
  }

  // ---- write partials (o rows = 4g+i; m,l live at lane r = row) ----
#pragma unroll
  for (int nf = 0; nf < 4; ++nf)
#pragma unroll
    for (int i = 0; i < 4; ++i)
      plo[w][4 * g + i][nf * 16 + r] = o[nf][i];
  if (g == 0) {
    pml[w][0][r] = m;
    pml[w][1][r] = l;
  }
  __syncthreads();

  // ---- merge the two kv-halves; each wave writes 8 rows of one q-tile ----
  const int base = (w >> 1) << 1;
  const int hlf = w & 1;
  const int qq0 = ((base == 0) ? j : (127 - j)) << 4;
#pragma unroll
  for (int rr = 0; rr < 8; ++rr) {
    const int row = hlf * 8 + rr;
    const float mA = pml[base][0][row], mB = pml[base + 1][0][row];
    const float lA = pml[base][1][row], lB = pml[base + 1][1][row];
    const float M = fmaxf(mA, mB);
    const float ea = exp2f(mA - M), eb = exp2f(mB - M);
    const float inv = 1.f / (lA * ea + lB * eb);
    const float oo = plo[base][row][lane] * ea + plo[base + 1][row][lane] * eb;
    out[((long)(b * S_ + qq0 + row)) * H_ + lane] = oo * inv;
  }
}

extern "C" void kernel_launch(void* const* d_in, const int* in_sizes, int n_in,
                              void* d_out, int out_size, void* d_ws, size_t ws_size,
                              hipStream_t stream) {
  const float* x  = (const float*)d_in[0];
  const float* Wk = (const float*)d_in[1];
  const float* Wq = (const float*)d_in[2];
  const float* Wv = (const float*)d_in[3];
  float* out = (float*)d_out;

  u16* Qb = (u16*)d_ws;                                   // 2 MiB
  u16* Kb = Qb + (long)B_ * S_ * H_;                      // 2 MiB
  u16* Vt = Kb + (long)B_ * S_ * H_;                      // 2 MiB
  u16* Wt = Vt + (long)B_ * S_ * H_;                      // 384 KiB

  wprep_kernel<<<48, 256, 0, stream>>>(Wk, Wq, Wv, Wt);
  qkv_kernel<<<512, 512, 0, stream>>>(x, Wt, Qb, Kb, Vt);
  attn7_kernel<<<B_ * 64, 256, 0, stream>>>(Qb, Kb, Vt, out);
}